// Round 8
// baseline (441.251 us; speedup 1.0000x reference)
//
#include <hip/hip_runtime.h>
#include <hip/hip_bf16.h>

#define B_  8
#define C_  256
#define CI_ 128
#define N_  4096

typedef __bf16 bf16;
typedef __attribute__((ext_vector_type(8))) __bf16 bf16x8;
typedef __attribute__((ext_vector_type(4))) __bf16 bf16x4;
typedef __attribute__((ext_vector_type(4))) float  floatx4;

static_assert(sizeof(bf16) == 2, "bf16 size");

__device__ inline floatx4 mfma16(bf16x8 a, bf16x8 b, floatx4 c) {
    return __builtin_amdgcn_mfma_f32_16x16x32_bf16(a, b, c, 0, 0, 0);
}

// ---------------------------------------------------------------------------
// Runtime dtype detection (inputs measured fp32; probe kept for robustness).
// ---------------------------------------------------------------------------
__device__ inline bool detect_fp32(const void* probe) {
    const unsigned short* u = (const unsigned short*)probe;
    int lane = threadIdx.x & 63;
    unsigned short w = u[lane * 2];
    int ex = (w >> 7) & 0xFF;
    bool insane = !((ex > 96 && ex < 143) || (w & 0x7FFF) == 0);
    unsigned long long b = __ballot(insane);
    return __popcll(b) > 16;
}

__device__ inline bf16x8 load8(const void* p, size_t i, bool fp32) {
    if (!fp32) return *(const bf16x8*)((const bf16*)p + i);
    const float* f = (const float*)p + i;
    floatx4 a = *(const floatx4*)(f);
    floatx4 c = *(const floatx4*)(f + 4);
    bf16x8 r;
    r[0] = (bf16)a[0]; r[1] = (bf16)a[1]; r[2] = (bf16)a[2]; r[3] = (bf16)a[3];
    r[4] = (bf16)c[0]; r[5] = (bf16)c[1]; r[6] = (bf16)c[2]; r[7] = (bf16)c[3];
    return r;
}

__device__ inline float loadv(const void* p, size_t i, bool fp32) {
    return fp32 ? ((const float*)p)[i] : (float)((const bf16*)p)[i];
}

__device__ inline bf16x8 cvt8(floatx4 a, floatx4 b) {
    bf16x8 r;
    r[0] = (bf16)a[0]; r[1] = (bf16)a[1]; r[2] = (bf16)a[2]; r[3] = (bf16)a[3];
    r[4] = (bf16)b[0]; r[5] = (bf16)b[1]; r[6] = (bf16)b[2]; r[7] = (bf16)b[3];
    return r;
}

// ---------------------------------------------------------------------------
// Kernel 1: three 1x1-conv projections in one block per 128-px tile.
// (Round-4 verified; ~36 us actual per round-6 attribution. Unchanged.)
// ---------------------------------------------------------------------------
__global__ __launch_bounds__(512) void proj3_kernel(
    const void* __restrict__ x,
    const void* __restrict__ wt, const void* __restrict__ bt,
    const void* __restrict__ wp, const void* __restrict__ bp,
    const void* __restrict__ wg, const void* __restrict__ bg,
    bf16* __restrict__ T, bf16* __restrict__ P, bf16* __restrict__ G)
{
    const bool fp32 = detect_fp32(x);

    const int b  = blockIdx.y;
    const int n0 = blockIdx.x * 128;

    __shared__ bf16 xT[128][40];
    __shared__ bf16 wl[384][40];

    const int t    = threadIdx.x;
    const int w    = t >> 6;
    const int lane = t & 63;
    const int l15  = lane & 15;
    const int quad = lane >> 4;
    const int wm   = w >> 1;     // R 16-slice within each 64-block
    const int wn   = w & 1;      // px half

    const int sc = t >> 4;       // staging channel 0..31
    const int sm = t & 15;       // staging px-octet
    const int wr = t >> 2;       // w-staging row 0..127
    const int wc = (t & 3) * 8;

    floatx4 acc[6][4];
#pragma unroll
    for (int f = 0; f < 6; ++f)
#pragma unroll
        for (int ni = 0; ni < 4; ++ni) acc[f][ni] = (floatx4)0.f;

    floatx4 pxa, pxb; bf16x8 pxh;
    floatx4 pwa[3], pwb[3]; bf16x8 pwh[3];

    auto issue = [&](int k) {
        size_t xo = ((size_t)b * C_ + k + sc) * N_ + n0 + sm * 8;
        if (fp32) {
            const float* fx_ = (const float*)x + xo;
            pxa = *(const floatx4*)fx_;
            pxb = *(const floatx4*)(fx_ + 4);
        } else {
            pxh = *(const bf16x8*)((const bf16*)x + xo);
        }
#pragma unroll
        for (int p = 0; p < 3; ++p) {
            const void* ws = (p == 0) ? wt : (p == 1) ? wp : wg;
            size_t wo = (size_t)wr * C_ + k + wc;
            if (fp32) {
                const float* fw_ = (const float*)ws + wo;
                pwa[p] = *(const floatx4*)fw_;
                pwb[p] = *(const floatx4*)(fw_ + 4);
            } else {
                pwh[p] = *(const bf16x8*)((const bf16*)ws + wo);
            }
        }
    };

    issue(0);

    for (int ks = 0; ks < 8; ++ks) {
        {
            bf16x8 xv = fp32 ? cvt8(pxa, pxb) : pxh;
            int colx = ((((sc >> 3) + sm) & 3) << 3) + (sc & 7);
#pragma unroll
            for (int i = 0; i < 8; ++i) xT[sm * 8 + i][colx] = xv[i];
#pragma unroll
            for (int p = 0; p < 3; ++p) {
                bf16x8 wv = fp32 ? cvt8(pwa[p], pwb[p]) : pwh[p];
                *(bf16x8*)(&wl[p * 128 + wr][wc]) = wv;
            }
        }
        __syncthreads();

        if (ks < 7) issue((ks + 1) * 32);

        bf16x8 fxr[4], fwr[6];
#pragma unroll
        for (int ni = 0; ni < 4; ++ni) {
            int px = wn * 64 + ni * 16 + l15;
            int ch = (quad + (px >> 3)) & 3;
            fxr[ni] = *(const bf16x8*)(&xT[px][ch * 8]);
        }
#pragma unroll
        for (int f = 0; f < 6; ++f)
            fwr[f] = *(const bf16x8*)(&wl[f * 64 + wm * 16 + l15][quad * 8]);

#pragma unroll
        for (int f = 0; f < 4; ++f)
#pragma unroll
            for (int ni = 0; ni < 4; ++ni)
                acc[f][ni] = mfma16(fxr[ni], fwr[f], acc[f][ni]);
#pragma unroll
        for (int f = 4; f < 6; ++f)
#pragma unroll
            for (int ni = 0; ni < 4; ++ni)
                acc[f][ni] = mfma16(fwr[f], fxr[ni], acc[f][ni]);

        __syncthreads();
    }

    // ---- epilogue: bias + store ----
#pragma unroll
    for (int f = 0; f < 6; ++f) {
        const void* bsel = (f < 2) ? bt : (f < 4) ? bp : bg;
        if (f < 4) {
            bf16* outp = ((f < 2) ? T : P) + (size_t)b * N_ * CI_;
            int o = (f & 1) * 64 + wm * 16 + l15;
            float bv = loadv(bsel, o, fp32);
#pragma unroll
            for (int ni = 0; ni < 4; ++ni)
#pragma unroll
                for (int r = 0; r < 4; ++r) {
                    int px = n0 + wn * 64 + ni * 16 + quad * 4 + r;
                    outp[(size_t)px * CI_ + o] = (bf16)(acc[f][ni][r] + bv);
                }
        } else {
            bf16* outp = G + (size_t)b * CI_ * N_;
#pragma unroll
            for (int r = 0; r < 4; ++r) {
                int o = (f & 1) * 64 + wm * 16 + quad * 4 + r;
                float bv = loadv(bsel, o, fp32);
#pragma unroll
                for (int ni = 0; ni < 4; ++ni) {
                    int px = n0 + wn * 64 + ni * 16 + l15;
                    outp[(size_t)o * N_ + px] = (bf16)(acc[f][ni][r] + bv);
                }
            }
        }
    }
}

// ---------------------------------------------------------------------------
// Kernel 2: flash attention v8 — round-4 structure (j-split + fused W GEMM +
// residual), setprio REVERTED (r7: −26 us in lockstep barrier structure,
// m190-consistent), and ALL LDS row strides moved out of the ≡4 mod 32 dw
// class that made every fragment read 8-way bank-conflicted:
//   Kl [64][136]->[64][140]  (70 dw ≡ 6 mod 32)
//   Vt [128][72]->[128][76]  (38 dw ≡ 6 mod 32)
//   Pw [32][76]              (38 dw, kept from r7 — fixed read 8-way + write
//                             4-way there)
// Fragment bank = 6*l15 + 4*quad mod 32 -> >=16 distinct banks, ~2-way
// residual (free per m136).
// LDS map: group region (Kl 17920 + Vt 19456 = 37376) @ g*37376;
//   Pw @ 74752 + w*4864 (ends 113664);
//   combine: scrO@0 (65536), scrL@65536 (8192), Yl@108544 (34816),
//   Wl@0 (69632, after scrO/scrL reads — barrier-separated).
// ---------------------------------------------------------------------------
__global__ __launch_bounds__(512) void attn_kernel(
    const bf16* __restrict__ T,   // [B][N][CI]
    const bf16* __restrict__ P,   // [B][N][CI]
    const bf16* __restrict__ G,   // [B][CI][N]
    const void* __restrict__ Ww,  // [C][CI]
    const void* __restrict__ Wb,  // [C]
    const void* __restrict__ x,   // [B][C][N]
    void* __restrict__ out)       // [B][C][N]
{
    const int bid = blockIdx.x;
    const int b   = bid & 7;            // XCD-aligned under %8 dispatch
    const int i0  = (bid >> 3) * 128;

    __shared__ __align__(16) char smem[143360];

    const bool fp32 = detect_fp32(x);

    const int t    = threadIdx.x;
    const int w    = t >> 6;            // 0..7
    const int g    = w >> 2;            // j-half group
    const int wg   = w & 3;             // wave within group
    const int tg   = t & 255;           // thread within group
    const int lane = t & 63;
    const int l15  = lane & 15;
    const int quad = lane >> 4;

    bf16* Kl = (bf16*)(smem + g * 37376);           // [64][140]
    bf16* Vt = (bf16*)(smem + g * 37376 + 17920);   // [128][76]
    bf16* Pw = (bf16*)(smem + 74752 + w * 4864);    // [32][76]

    const bf16* Kb = P + (size_t)b * N_ * CI_;
    const bf16* Vb = G + (size_t)b * CI_ * N_;
    const int jbase = g * 2048;

    bf16x8 qf[2][4];
#pragma unroll
    for (int rf = 0; rf < 2; ++rf) {
        const bf16* Qb = T + ((size_t)b * N_ + i0 + wg * 32 + rf * 16 + l15) * CI_;
#pragma unroll
        for (int ks = 0; ks < 4; ++ks)
            qf[rf][ks] = *(const bf16x8*)(Qb + ks * 32 + quad * 8);
    }

    floatx4 O[2][8];
#pragma unroll
    for (int rf = 0; rf < 2; ++rf)
#pragma unroll
        for (int cf = 0; cf < 8; ++cf) O[rf][cf] = (floatx4)0.f;
    float lsum[2][4];
#pragma unroll
    for (int rf = 0; rf < 2; ++rf)
#pragma unroll
        for (int r = 0; r < 4; ++r) lsum[rf][r] = 0.f;

    bf16x8 kreg[4], vreg[4];
#pragma unroll
    for (int s = 0; s < 4; ++s) {
        int id = tg + s * 256;
        kreg[s] = *(const bf16x8*)(Kb + (size_t)(jbase + (id >> 4)) * CI_ + (id & 15) * 8);
        vreg[s] = *(const bf16x8*)(Vb + (size_t)(id >> 3) * N_ + jbase + (id & 7) * 8);
    }

    for (int it = 0; it < 32; ++it) {
#pragma unroll
        for (int s = 0; s < 4; ++s) {
            int id = tg + s * 256;
            *(bf16x8*)(Kl + (id >> 4) * 140 + (id & 15) * 8) = kreg[s];
            *(bf16x8*)(Vt + (id >> 3) * 76 + (id & 7) * 8) = vreg[s];
        }
        __syncthreads();

        if (it < 31) {
            int j0n = jbase + (it + 1) * 64;
#pragma unroll
            for (int s = 0; s < 4; ++s) {
                int id = tg + s * 256;
                kreg[s] = *(const bf16x8*)(Kb + (size_t)(j0n + (id >> 4)) * CI_ + (id & 15) * 8);
                vreg[s] = *(const bf16x8*)(Vb + (size_t)(id >> 3) * N_ + j0n + (id & 7) * 8);
            }
        }

        // S = Q K^T
        floatx4 S[2][4];
#pragma unroll
        for (int jf = 0; jf < 4; ++jf) {
            floatx4 s0 = (floatx4)0.f, s1 = (floatx4)0.f;
#pragma unroll
            for (int ks = 0; ks < 4; ++ks) {
                bf16x8 kf = *(const bf16x8*)(Kl + (jf * 16 + l15) * 140 + ks * 32 + quad * 8);
                s0 = mfma16(qf[0][ks], kf, s0);
                s1 = mfma16(qf[1][ks], kf, s1);
            }
            S[0][jf] = s0;
            S[1][jf] = s1;
        }

        // P = exp(S); per-lane partial l; bf16 P to per-wave LDS (A-layout)
#pragma unroll
        for (int rf = 0; rf < 2; ++rf)
#pragma unroll
            for (int r = 0; r < 4; ++r) {
                float p0 = __expf(S[rf][0][r]);
                float p1 = __expf(S[rf][1][r]);
                float p2 = __expf(S[rf][2][r]);
                float p3 = __expf(S[rf][3][r]);
                lsum[rf][r] += (p0 + p1) + (p2 + p3);
                int row = rf * 16 + quad * 4 + r;
                Pw[row * 76 + 0 * 16 + l15] = (bf16)p0;
                Pw[row * 76 + 1 * 16 + l15] = (bf16)p1;
                Pw[row * 76 + 2 * 16 + l15] = (bf16)p2;
                Pw[row * 76 + 3 * 16 + l15] = (bf16)p3;
            }

        // O += P V
#pragma unroll
        for (int ks = 0; ks < 2; ++ks) {
            bf16x8 pf0 = *(const bf16x8*)(Pw + l15 * 76 + ks * 32 + quad * 8);
            bf16x8 pf1 = *(const bf16x8*)(Pw + (16 + l15) * 76 + ks * 32 + quad * 8);
#pragma unroll
            for (int cf = 0; cf < 8; ++cf) {
                bf16x8 vf = *(const bf16x8*)(Vt + (cf * 16 + l15) * 76 + ks * 32 + quad * 8);
                O[0][cf] = mfma16(pf0, vf, O[0][cf]);
                O[1][cf] = mfma16(pf1, vf, O[1][cf]);
            }
        }
        __syncthreads();
    }

    // ---- combine group 1 partials into group 0 via (now dead) stage LDS ----
    float* scrO = (float*)smem;             // [64][256] f32 = 65536 B
    float* scrL = (float*)(smem + 65536);   // [8][256]  f32 =  8192 B
    bf16*  Yl   = (bf16*)(smem + 108544);   // [128][136] bf16 = 34816 B
    if (g == 1) {
#pragma unroll
        for (int rf = 0; rf < 2; ++rf)
#pragma unroll
            for (int cf = 0; cf < 8; ++cf)
#pragma unroll
                for (int r = 0; r < 4; ++r)
                    scrO[(rf * 32 + cf * 4 + r) * 256 + wg * 64 + lane] = O[rf][cf][r];
#pragma unroll
        for (int rf = 0; rf < 2; ++rf)
#pragma unroll
            for (int r = 0; r < 4; ++r)
                scrL[(rf * 4 + r) * 256 + wg * 64 + lane] = lsum[rf][r];
    }
    __syncthreads();
    if (g == 0) {
#pragma unroll
        for (int rf = 0; rf < 2; ++rf)
#pragma unroll
            for (int cf = 0; cf < 8; ++cf)
#pragma unroll
                for (int r = 0; r < 4; ++r)
                    O[rf][cf][r] += scrO[(rf * 32 + cf * 4 + r) * 256 + wg * 64 + lane];

        // one-time l reduction across the 16 lanes sharing each row
#pragma unroll
        for (int rf = 0; rf < 2; ++rf)
#pragma unroll
            for (int r = 0; r < 4; ++r) {
                float rs = lsum[rf][r] + scrL[(rf * 4 + r) * 256 + wg * 64 + lane];
                rs += __shfl_xor(rs, 1);
                rs += __shfl_xor(rs, 2);
                rs += __shfl_xor(rs, 4);
                rs += __shfl_xor(rs, 8);
                lsum[rf][r] = 1.f / rs;
            }

        // normalized bf16 Y-tile into LDS (row = px-local, col = ci)
#pragma unroll
        for (int rf = 0; rf < 2; ++rf)
#pragma unroll
            for (int cf = 0; cf < 8; ++cf)
#pragma unroll
                for (int r = 0; r < 4; ++r) {
                    int px = wg * 32 + rf * 16 + quad * 4 + r;
                    Yl[px * 136 + cf * 16 + l15] =
                        (bf16)(O[rf][cf][r] * lsum[rf][r]);
                }
    }
    __syncthreads();

    // ---- stage W_w -> Wl bf16 [256][136] over the dead staging region ----
    bf16* Wl = (bf16*)smem;
#pragma unroll
    for (int p = 0; p < 16; ++p) {
        int idx = p * 2048 + t * 4;          // 512 thr x 4 elems x 16 passes
        int o   = idx >> 7;
        int ci  = idx & 127;
        bf16x4 v;
        if (fp32) {
            floatx4 f4 = *(const floatx4*)((const float*)Ww + idx);
            v[0] = (bf16)f4[0]; v[1] = (bf16)f4[1];
            v[2] = (bf16)f4[2]; v[3] = (bf16)f4[3];
        } else {
            v = *(const bf16x4*)((const bf16*)Ww + idx);
        }
        *(bf16x4*)(&Wl[o * 136 + ci]) = v;
    }
    __syncthreads();

    // ---- out[o][px] = Ww @ Y + Wb + x : 8 waves = 4(o) x 2(px) of 64x64 ----
    {
        const int wm = w >> 1;   // o 64-block
        const int wn = w & 1;    // px 64-block
        floatx4 acc[4][4];
#pragma unroll
        for (int i = 0; i < 4; ++i)
#pragma unroll
            for (int j = 0; j < 4; ++j) acc[i][j] = (floatx4)0.f;

#pragma unroll
        for (int ks = 0; ks < 4; ++ks) {
            bf16x8 fa[4], fb[4];
#pragma unroll
            for (int i = 0; i < 4; ++i) {
                fa[i] = *(const bf16x8*)(&Wl[(wm * 64 + i * 16 + l15) * 136 + ks * 32 + quad * 8]);
                fb[i] = *(const bf16x8*)(&Yl[(wn * 64 + i * 16 + l15) * 136 + ks * 32 + quad * 8]);
            }
#pragma unroll
            for (int mi = 0; mi < 4; ++mi)
#pragma unroll
                for (int ni = 0; ni < 4; ++ni)
                    acc[mi][ni] = mfma16(fa[mi], fb[ni], acc[mi][ni]);
        }

#pragma unroll
        for (int mi = 0; mi < 4; ++mi)
#pragma unroll
            for (int ni = 0; ni < 4; ++ni)
#pragma unroll
                for (int r = 0; r < 4; ++r) {
                    int oo = wm * 64 + mi * 16 + quad * 4 + r;
                    int px = i0 + wn * 64 + ni * 16 + l15;
                    size_t idx = ((size_t)b * C_ + oo) * N_ + px;
                    float v = acc[mi][ni][r] + loadv(Wb, oo, fp32)
                            + loadv(x, idx, fp32);
                    if (fp32) ((float*)out)[idx] = v;
                    else      ((bf16*)out)[idx] = (bf16)v;
                }
    }
}

// ---------------------------------------------------------------------------
extern "C" void kernel_launch(void* const* d_in, const int* in_sizes, int n_in,
                              void* d_out, int out_size, void* d_ws, size_t ws_size,
                              hipStream_t stream) {
    const void* x    = d_in[0];
    const void* g_w  = d_in[1];
    const void* g_b  = d_in[2];
    const void* th_w = d_in[3];
    const void* th_b = d_in[4];
    const void* ph_w = d_in[5];
    const void* ph_b = d_in[6];
    const void* W_w  = d_in[7];
    const void* W_b  = d_in[8];

    const size_t plane = (size_t)B_ * N_ * CI_;
    bf16* T = (bf16*)d_ws;
    bf16* P = T + plane;
    bf16* G = P + plane;

    proj3_kernel<<<dim3(N_ / 128, B_), 512, 0, stream>>>(
        x, th_w, th_b, ph_w, ph_b, g_w, g_b, T, P, G);
    attn_kernel<<<dim3(N_ / 128 * B_), 512, 0, stream>>>(
        T, P, G, W_w, W_b, x, d_out);
}

// Round 9
// 215.161 us; speedup vs baseline: 2.0508x; 2.0508x over previous
//
#include <hip/hip_runtime.h>
#include <hip/hip_bf16.h>

#define B_  8
#define C_  256
#define CI_ 128
#define N_  4096

typedef __bf16 bf16;
typedef __attribute__((ext_vector_type(8))) __bf16 bf16x8;
typedef __attribute__((ext_vector_type(4))) __bf16 bf16x4;
typedef __attribute__((ext_vector_type(4))) float  floatx4;

static_assert(sizeof(bf16) == 2, "bf16 size");

__device__ inline floatx4 mfma16(bf16x8 a, bf16x8 b, floatx4 c) {
    return __builtin_amdgcn_mfma_f32_16x16x32_bf16(a, b, c, 0, 0, 0);
}

// ---------------------------------------------------------------------------
// Runtime dtype detection (inputs measured fp32; probe kept for robustness).
// ---------------------------------------------------------------------------
__device__ inline bool detect_fp32(const void* probe) {
    const unsigned short* u = (const unsigned short*)probe;
    int lane = threadIdx.x & 63;
    unsigned short w = u[lane * 2];
    int ex = (w >> 7) & 0xFF;
    bool insane = !((ex > 96 && ex < 143) || (w & 0x7FFF) == 0);
    unsigned long long b = __ballot(insane);
    return __popcll(b) > 16;
}

__device__ inline bf16x8 load8(const void* p, size_t i, bool fp32) {
    if (!fp32) return *(const bf16x8*)((const bf16*)p + i);
    const float* f = (const float*)p + i;
    floatx4 a = *(const floatx4*)(f);
    floatx4 c = *(const floatx4*)(f + 4);
    bf16x8 r;
    r[0] = (bf16)a[0]; r[1] = (bf16)a[1]; r[2] = (bf16)a[2]; r[3] = (bf16)a[3];
    r[4] = (bf16)c[0]; r[5] = (bf16)c[1]; r[6] = (bf16)c[2]; r[7] = (bf16)c[3];
    return r;
}

__device__ inline float loadv(const void* p, size_t i, bool fp32) {
    return fp32 ? ((const float*)p)[i] : (float)((const bf16*)p)[i];
}

__device__ inline bf16x8 cvt8(floatx4 a, floatx4 b) {
    bf16x8 r;
    r[0] = (bf16)a[0]; r[1] = (bf16)a[1]; r[2] = (bf16)a[2]; r[3] = (bf16)a[3];
    r[4] = (bf16)b[0]; r[5] = (bf16)b[1]; r[6] = (bf16)b[2]; r[7] = (bf16)b[3];
    return r;
}

// ---------------------------------------------------------------------------
// Kernel 1: three 1x1-conv projections in one block per 128-px tile.
// (Round-4 verified, ~36 us actual. Unchanged.)
// ---------------------------------------------------------------------------
__global__ __launch_bounds__(512) void proj3_kernel(
    const void* __restrict__ x,
    const void* __restrict__ wt, const void* __restrict__ bt,
    const void* __restrict__ wp, const void* __restrict__ bp,
    const void* __restrict__ wg, const void* __restrict__ bg,
    bf16* __restrict__ T, bf16* __restrict__ P, bf16* __restrict__ G)
{
    const bool fp32 = detect_fp32(x);

    const int b  = blockIdx.y;
    const int n0 = blockIdx.x * 128;

    __shared__ bf16 xT[128][40];
    __shared__ bf16 wl[384][40];

    const int t    = threadIdx.x;
    const int w    = t >> 6;
    const int lane = t & 63;
    const int l15  = lane & 15;
    const int quad = lane >> 4;
    const int wm   = w >> 1;     // R 16-slice within each 64-block
    const int wn   = w & 1;      // px half

    const int sc = t >> 4;       // staging channel 0..31
    const int sm = t & 15;       // staging px-octet
    const int wr = t >> 2;       // w-staging row 0..127
    const int wc = (t & 3) * 8;

    floatx4 acc[6][4];
#pragma unroll
    for (int f = 0; f < 6; ++f)
#pragma unroll
        for (int ni = 0; ni < 4; ++ni) acc[f][ni] = (floatx4)0.f;

    floatx4 pxa, pxb; bf16x8 pxh;
    floatx4 pwa[3], pwb[3]; bf16x8 pwh[3];

    auto issue = [&](int k) {
        size_t xo = ((size_t)b * C_ + k + sc) * N_ + n0 + sm * 8;
        if (fp32) {
            const float* fx_ = (const float*)x + xo;
            pxa = *(const floatx4*)fx_;
            pxb = *(const floatx4*)(fx_ + 4);
        } else {
            pxh = *(const bf16x8*)((const bf16*)x + xo);
        }
#pragma unroll
        for (int p = 0; p < 3; ++p) {
            const void* ws = (p == 0) ? wt : (p == 1) ? wp : wg;
            size_t wo = (size_t)wr * C_ + k + wc;
            if (fp32) {
                const float* fw_ = (const float*)ws + wo;
                pwa[p] = *(const floatx4*)fw_;
                pwb[p] = *(const floatx4*)(fw_ + 4);
            } else {
                pwh[p] = *(const bf16x8*)((const bf16*)ws + wo);
            }
        }
    };

    issue(0);

    for (int ks = 0; ks < 8; ++ks) {
        {
            bf16x8 xv = fp32 ? cvt8(pxa, pxb) : pxh;
            int colx = ((((sc >> 3) + sm) & 3) << 3) + (sc & 7);
#pragma unroll
            for (int i = 0; i < 8; ++i) xT[sm * 8 + i][colx] = xv[i];
#pragma unroll
            for (int p = 0; p < 3; ++p) {
                bf16x8 wv = fp32 ? cvt8(pwa[p], pwb[p]) : pwh[p];
                *(bf16x8*)(&wl[p * 128 + wr][wc]) = wv;
            }
        }
        __syncthreads();

        if (ks < 7) issue((ks + 1) * 32);

        bf16x8 fxr[4], fwr[6];
#pragma unroll
        for (int ni = 0; ni < 4; ++ni) {
            int px = wn * 64 + ni * 16 + l15;
            int ch = (quad + (px >> 3)) & 3;
            fxr[ni] = *(const bf16x8*)(&xT[px][ch * 8]);
        }
#pragma unroll
        for (int f = 0; f < 6; ++f)
            fwr[f] = *(const bf16x8*)(&wl[f * 64 + wm * 16 + l15][quad * 8]);

#pragma unroll
        for (int f = 0; f < 4; ++f)
#pragma unroll
            for (int ni = 0; ni < 4; ++ni)
                acc[f][ni] = mfma16(fxr[ni], fwr[f], acc[f][ni]);
#pragma unroll
        for (int f = 4; f < 6; ++f)
#pragma unroll
            for (int ni = 0; ni < 4; ++ni)
                acc[f][ni] = mfma16(fwr[f], fxr[ni], acc[f][ni]);

        __syncthreads();
    }

    // ---- epilogue: bias + store ----
#pragma unroll
    for (int f = 0; f < 6; ++f) {
        const void* bsel = (f < 2) ? bt : (f < 4) ? bp : bg;
        if (f < 4) {
            bf16* outp = ((f < 2) ? T : P) + (size_t)b * N_ * CI_;
            int o = (f & 1) * 64 + wm * 16 + l15;
            float bv = loadv(bsel, o, fp32);
#pragma unroll
            for (int ni = 0; ni < 4; ++ni)
#pragma unroll
                for (int r = 0; r < 4; ++r) {
                    int px = n0 + wn * 64 + ni * 16 + quad * 4 + r;
                    outp[(size_t)px * CI_ + o] = (bf16)(acc[f][ni][r] + bv);
                }
        } else {
            bf16* outp = G + (size_t)b * CI_ * N_;
#pragma unroll
            for (int r = 0; r < 4; ++r) {
                int o = (f & 1) * 64 + wm * 16 + quad * 4 + r;
                float bv = loadv(bsel, o, fp32);
#pragma unroll
                for (int ni = 0; ni < 4; ++ni) {
                    int px = n0 + wn * 64 + ni * 16 + l15;
                    outp[(size_t)o * N_ + px] = (bf16)(acc[f][ni][r] + bv);
                }
            }
        }
    }
}

// ---------------------------------------------------------------------------
// Kernel 2: flash attention v9 — exact round-4 structure (121 us verified),
// with the m214-PROVEN LDS XOR swizzle instead of stride padding:
//   Kl [64][128], Vt [128][64], Pw [32][64] — strides 256/128/128 B (all
//   16B multiples: round-8's misalignment regression is impossible by
//   construction) — and every 16B chunk index XORed with (row&7) on BOTH
//   writer and reader. Unswizzled stride-128B would be a 16-way conflict;
//   swizzled, this is exactly the m214 [64][128] case (+89% there).
// Round-7/8 lessons encoded: no setprio (lockstep barriers, m190); strides
//   stay 16B-aligned; pencil bank-models distrusted — proven recipe only.
// LDS map (133120 B total):
//   loop:    Kl/Vt @ g*32768 (16384 each); Pw @ 65536 + w*4096 (ends 98304)
//   combine: scrO@0 (65536, over dead K/V), scrL@65536 (8192, over dead Pw
//            w0/w1), Yl@98304 (34816)  [all barrier-separated]
//   final:   Wl@0 (69632, after scrO/scrL reads)
// ---------------------------------------------------------------------------
__global__ __launch_bounds__(512) void attn_kernel(
    const bf16* __restrict__ T,   // [B][N][CI]
    const bf16* __restrict__ P,   // [B][N][CI]
    const bf16* __restrict__ G,   // [B][CI][N]
    const void* __restrict__ Ww,  // [C][CI]
    const void* __restrict__ Wb,  // [C]
    const void* __restrict__ x,   // [B][C][N]
    void* __restrict__ out)       // [B][C][N]
{
    const int bid = blockIdx.x;
    const int b   = bid & 7;            // XCD-aligned under %8 dispatch
    const int i0  = (bid >> 3) * 128;

    __shared__ __align__(16) char smem[133120];

    const bool fp32 = detect_fp32(x);

    const int t    = threadIdx.x;
    const int w    = t >> 6;            // 0..7
    const int g    = w >> 2;            // j-half group
    const int wg   = w & 3;             // wave within group
    const int tg   = t & 255;           // thread within group
    const int lane = t & 63;
    const int l15  = lane & 15;
    const int quad = lane >> 4;
    const int m7   = l15 & 7;           // XOR mask for fragment reads

    bf16* Kl = (bf16*)(smem + g * 32768);           // [64][128]  swizzled
    bf16* Vt = (bf16*)(smem + g * 32768 + 16384);   // [128][64]  swizzled
    bf16* Pw = (bf16*)(smem + 65536 + w * 4096);    // [32][64]   swizzled

    const bf16* Kb = P + (size_t)b * N_ * CI_;
    const bf16* Vb = G + (size_t)b * CI_ * N_;
    const int jbase = g * 2048;

    bf16x8 qf[2][4];
#pragma unroll
    for (int rf = 0; rf < 2; ++rf) {
        const bf16* Qb = T + ((size_t)b * N_ + i0 + wg * 32 + rf * 16 + l15) * CI_;
#pragma unroll
        for (int ks = 0; ks < 4; ++ks)
            qf[rf][ks] = *(const bf16x8*)(Qb + ks * 32 + quad * 8);
    }

    floatx4 O[2][8];
#pragma unroll
    for (int rf = 0; rf < 2; ++rf)
#pragma unroll
        for (int cf = 0; cf < 8; ++cf) O[rf][cf] = (floatx4)0.f;
    float lsum[2][4];
#pragma unroll
    for (int rf = 0; rf < 2; ++rf)
#pragma unroll
        for (int r = 0; r < 4; ++r) lsum[rf][r] = 0.f;

    bf16x8 kreg[4], vreg[4];
#pragma unroll
    for (int s = 0; s < 4; ++s) {
        int id = tg + s * 256;
        kreg[s] = *(const bf16x8*)(Kb + (size_t)(jbase + (id >> 4)) * CI_ + (id & 15) * 8);
        vreg[s] = *(const bf16x8*)(Vb + (size_t)(id >> 3) * N_ + jbase + (id & 7) * 8);
    }

    for (int it = 0; it < 32; ++it) {
        // staging: chunk index XORed with row&7 (writer side of swizzle)
#pragma unroll
        for (int s = 0; s < 4; ++s) {
            int id = tg + s * 256;
            int kr = id >> 4, kc = id & 15;
            int vr = id >> 3, vc = id & 7;
            *(bf16x8*)(Kl + kr * 128 + ((kc ^ (kr & 7)) * 8)) = kreg[s];
            *(bf16x8*)(Vt + vr * 64  + ((vc ^ (vr & 7)) * 8)) = vreg[s];
        }
        __syncthreads();

        if (it < 31) {
            int j0n = jbase + (it + 1) * 64;
#pragma unroll
            for (int s = 0; s < 4; ++s) {
                int id = tg + s * 256;
                kreg[s] = *(const bf16x8*)(Kb + (size_t)(j0n + (id >> 4)) * CI_ + (id & 15) * 8);
                vreg[s] = *(const bf16x8*)(Vb + (size_t)(id >> 3) * N_ + j0n + (id & 7) * 8);
            }
        }

        // S = Q K^T   (kf reader: chunk = ks*4+quad, XOR row&7 = l15&7)
        floatx4 S[2][4];
#pragma unroll
        for (int jf = 0; jf < 4; ++jf) {
            floatx4 s0 = (floatx4)0.f, s1 = (floatx4)0.f;
#pragma unroll
            for (int ks = 0; ks < 4; ++ks) {
                bf16x8 kf = *(const bf16x8*)(
                    Kl + (jf * 16 + l15) * 128 + (((ks * 4 + quad) ^ m7) * 8));
                s0 = mfma16(qf[0][ks], kf, s0);
                s1 = mfma16(qf[1][ks], kf, s1);
            }
            S[0][jf] = s0;
            S[1][jf] = s1;
        }

        // P = exp(S); per-lane partial l; bf16 P to per-wave swizzled LDS
        // writer: value jf at col jf*16+l15 -> chunk jf*2+(l15>>3), XOR row&7
#pragma unroll
        for (int rf = 0; rf < 2; ++rf)
#pragma unroll
            for (int r = 0; r < 4; ++r) {
                float p0 = __expf(S[rf][0][r]);
                float p1 = __expf(S[rf][1][r]);
                float p2 = __expf(S[rf][2][r]);
                float p3 = __expf(S[rf][3][r]);
                lsum[rf][r] += (p0 + p1) + (p2 + p3);
                int row = rf * 16 + quad * 4 + r;
                int r7  = (quad * 4 + r) & 7;
                int cb  = l15 >> 3;
                int base = row * 64 + (l15 & 7);
                Pw[base + ((0 + cb) ^ r7) * 8] = (bf16)p0;
                Pw[base + ((2 + cb) ^ r7) * 8] = (bf16)p1;
                Pw[base + ((4 + cb) ^ r7) * 8] = (bf16)p2;
                Pw[base + ((6 + cb) ^ r7) * 8] = (bf16)p3;
            }

        // O += P V  (pf/vf readers: chunk = ks*4+quad, XOR row&7)
#pragma unroll
        for (int ks = 0; ks < 2; ++ks) {
            int cx = ((ks * 4 + quad) ^ m7) * 8;
            bf16x8 pf0 = *(const bf16x8*)(Pw + l15 * 64 + cx);
            bf16x8 pf1 = *(const bf16x8*)(Pw + (16 + l15) * 64 + cx);
#pragma unroll
            for (int cf = 0; cf < 8; ++cf) {
                bf16x8 vf = *(const bf16x8*)(Vt + (cf * 16 + l15) * 64 + cx);
                O[0][cf] = mfma16(pf0, vf, O[0][cf]);
                O[1][cf] = mfma16(pf1, vf, O[1][cf]);
            }
        }
        __syncthreads();
    }

    // ---- combine group 1 partials into group 0 via (now dead) stage LDS ----
    float* scrO = (float*)smem;             // [64][256] f32 = 65536 B
    float* scrL = (float*)(smem + 65536);   // [8][256]  f32 =  8192 B
    bf16*  Yl   = (bf16*)(smem + 98304);    // [128][136] bf16 = 34816 B
    if (g == 1) {
#pragma unroll
        for (int rf = 0; rf < 2; ++rf)
#pragma unroll
            for (int cf = 0; cf < 8; ++cf)
#pragma unroll
                for (int r = 0; r < 4; ++r)
                    scrO[(rf * 32 + cf * 4 + r) * 256 + wg * 64 + lane] = O[rf][cf][r];
#pragma unroll
        for (int rf = 0; rf < 2; ++rf)
#pragma unroll
            for (int r = 0; r < 4; ++r)
                scrL[(rf * 4 + r) * 256 + wg * 64 + lane] = lsum[rf][r];
    }
    __syncthreads();
    if (g == 0) {
#pragma unroll
        for (int rf = 0; rf < 2; ++rf)
#pragma unroll
            for (int cf = 0; cf < 8; ++cf)
#pragma unroll
                for (int r = 0; r < 4; ++r)
                    O[rf][cf][r] += scrO[(rf * 32 + cf * 4 + r) * 256 + wg * 64 + lane];

        // one-time l reduction across the 16 lanes sharing each row
#pragma unroll
        for (int rf = 0; rf < 2; ++rf)
#pragma unroll
            for (int r = 0; r < 4; ++r) {
                float rs = lsum[rf][r] + scrL[(rf * 4 + r) * 256 + wg * 64 + lane];
                rs += __shfl_xor(rs, 1);
                rs += __shfl_xor(rs, 2);
                rs += __shfl_xor(rs, 4);
                rs += __shfl_xor(rs, 8);
                lsum[rf][r] = 1.f / rs;
            }

        // normalized bf16 Y-tile into LDS (row = px-local, col = ci)
#pragma unroll
        for (int rf = 0; rf < 2; ++rf)
#pragma unroll
            for (int cf = 0; cf < 8; ++cf)
#pragma unroll
                for (int r = 0; r < 4; ++r) {
                    int px = wg * 32 + rf * 16 + quad * 4 + r;
                    Yl[px * 136 + cf * 16 + l15] =
                        (bf16)(O[rf][cf][r] * lsum[rf][r]);
                }
    }
    __syncthreads();

    // ---- stage W_w -> Wl bf16 [256][136] over the dead staging region ----
    bf16* Wl = (bf16*)smem;
#pragma unroll
    for (int p = 0; p < 16; ++p) {
        int idx = p * 2048 + t * 4;          // 512 thr x 4 elems x 16 passes
        int o   = idx >> 7;
        int ci  = idx & 127;
        bf16x4 v;
        if (fp32) {
            floatx4 f4 = *(const floatx4*)((const float*)Ww + idx);
            v[0] = (bf16)f4[0]; v[1] = (bf16)f4[1];
            v[2] = (bf16)f4[2]; v[3] = (bf16)f4[3];
        } else {
            v = *(const bf16x4*)((const bf16*)Ww + idx);
        }
        *(bf16x4*)(&Wl[o * 136 + ci]) = v;
    }
    __syncthreads();

    // ---- out[o][px] = Ww @ Y + Wb + x : 8 waves = 4(o) x 2(px) of 64x64 ----
    {
        const int wm = w >> 1;   // o 64-block
        const int wn = w & 1;    // px 64-block
        floatx4 acc[4][4];
#pragma unroll
        for (int i = 0; i < 4; ++i)
#pragma unroll
            for (int j = 0; j < 4; ++j) acc[i][j] = (floatx4)0.f;

#pragma unroll
        for (int ks = 0; ks < 4; ++ks) {
            bf16x8 fa[4], fb[4];
#pragma unroll
            for (int i = 0; i < 4; ++i) {
                fa[i] = *(const bf16x8*)(&Wl[(wm * 64 + i * 16 + l15) * 136 + ks * 32 + quad * 8]);
                fb[i] = *(const bf16x8*)(&Yl[(wn * 64 + i * 16 + l15) * 136 + ks * 32 + quad * 8]);
            }
#pragma unroll
            for (int mi = 0; mi < 4; ++mi)
#pragma unroll
                for (int ni = 0; ni < 4; ++ni)
                    acc[mi][ni] = mfma16(fa[mi], fb[ni], acc[mi][ni]);
        }

#pragma unroll
        for (int mi = 0; mi < 4; ++mi)
#pragma unroll
            for (int ni = 0; ni < 4; ++ni)
#pragma unroll
                for (int r = 0; r < 4; ++r) {
                    int oo = wm * 64 + mi * 16 + quad * 4 + r;
                    int px = i0 + wn * 64 + ni * 16 + l15;
                    size_t idx = ((size_t)b * C_ + oo) * N_ + px;
                    float v = acc[mi][ni][r] + loadv(Wb, oo, fp32)
                            + loadv(x, idx, fp32);
                    if (fp32) ((float*)out)[idx] = v;
                    else      ((bf16*)out)[idx] = (bf16)v;
                }
    }
}

// ---------------------------------------------------------------------------
extern "C" void kernel_launch(void* const* d_in, const int* in_sizes, int n_in,
                              void* d_out, int out_size, void* d_ws, size_t ws_size,
                              hipStream_t stream) {
    const void* x    = d_in[0];
    const void* g_w  = d_in[1];
    const void* g_b  = d_in[2];
    const void* th_w = d_in[3];
    const void* th_b = d_in[4];
    const void* ph_w = d_in[5];
    const void* ph_b = d_in[6];
    const void* W_w  = d_in[7];
    const void* W_b  = d_in[8];

    const size_t plane = (size_t)B_ * N_ * CI_;
    bf16* T = (bf16*)d_ws;
    bf16* P = T + plane;
    bf16* G = P + plane;

    proj3_kernel<<<dim3(N_ / 128, B_), 512, 0, stream>>>(
        x, th_w, th_b, ph_w, ph_b, g_w, g_b, T, P, G);
    attn_kernel<<<dim3(N_ / 128 * B_), 512, 0, stream>>>(
        T, P, G, W_w, W_b, x, d_out);
}